// Round 15
// baseline (106.711 us; speedup 1.0000x reference)
//
#include <hip/hip_runtime.h>

#define NBATCH 4
#define NROWS  100000
#define KD     16
#define EPSF   1e-6f
#define WCE    2.0f
#define WDICE  0.1f
#define NREP   8
#define LN2F   0.6931471805599453f
#define SRS    272   // super-row stride: 1024B data + 64B pad -> 2-way banks (free)

typedef __attribute__((ext_vector_type(8))) short short8;
typedef __attribute__((ext_vector_type(4))) float f32x4;

__device__ __forceinline__ unsigned short bf16rne(float x) {
  unsigned u = __float_as_uint(x);
  unsigned r = u + 0x7FFFu + ((u >> 16) & 1u);
  return (unsigned short)(r >> 16);
}

__device__ __forceinline__ void async_copy16(const float* g, float* l) {
  __builtin_amdgcn_global_load_lds(
      (const __attribute__((address_space(1))) float*)g,
      (__attribute__((address_space(3))) float*)l, 16, 0, 0);
}

// ---------------- accumulation kernel (byte-identical to round 14) ---------
__global__ __launch_bounds__(256, 4) void sml_accum(
    const float* __restrict__ mask, const float* __restrict__ gt,
    const float* __restrict__ valid, float* __restrict__ ws)
{
  const int b    = blockIdx.y;
  const int tid  = (int)threadIdx.x;
  const int lane = tid & 63;
  const int wv   = tid >> 6;
  const int q    = lane >> 4;      // quad: k-slice rows 8q..8q+7
  const int c    = lane & 15;      // feature / label column
  const int row0 = blockIdx.x * 256;

  __shared__ float sBuf[9216];
  float* sM = sBuf;                // staging: 16 super-rows x SRS
  float* sG = sBuf + 16 * SRS;     // staging: 16 super-rows x SRS

  const float* maskb  = mask  + (size_t)b * NROWS * KD;
  const float* gtb    = gt    + (size_t)b * NROWS * KD;
  const float* validb = valid + (size_t)b * NROWS;

#pragma unroll
  for (int i = 0; i < 4; ++i) {
    const int g   = i * 256 + tid;            // 16B chunk index (row*4 + colgrp)
    const int rg  = row0 + (g >> 2);
    const int rc  = (rg < NROWS) ? rg : (NROWS - 1);   // clamp tail
    const size_t off = (size_t)rc * KD + (size_t)(g & 3) * 4;
    const int dst = (g >> 6) * SRS + (g & 63) * 4;     // padded group placement
    async_copy16(maskb + off, &sM[dst]);
    async_copy16(gtb   + off, &sG[dst]);
  }

  // ---- hoisted valid loads (independent of LDS; overlap the stage drain) --
  float vv[2][8];
#pragma unroll
  for (int ch = 0; ch < 2; ++ch) {
    const int grow = row0 + wv * 64 + ch * 32 + 8 * q;
    if (grow + 7 < NROWS) {
      const float4 va  = *(const float4*)(validb + grow);
      const float4 vb4 = *(const float4*)(validb + grow + 4);
      vv[ch][0] = va.x;  vv[ch][1] = va.y;  vv[ch][2] = va.z;  vv[ch][3] = va.w;
      vv[ch][4] = vb4.x; vv[ch][5] = vb4.y; vv[ch][6] = vb4.z; vv[ch][7] = vb4.w;
    } else {
#pragma unroll
      for (int t = 0; t < 8; ++t)
        vv[ch][t] = (grow + t < NROWS) ? validb[grow + t] : 0.f;
    }
  }
  __syncthreads();

  f32x4 accP = {0.f, 0.f, 0.f, 0.f};
  f32x4 accQ = {0.f, 0.f, 0.f, 0.f};
  f32x4 accI = {0.f, 0.f, 0.f, 0.f};

#pragma unroll
  for (int ch = 0; ch < 2; ++ch) {
    const int rt = wv * 64 + ch * 32 + 8 * q;    // block-local row of this quad
    float m[8], g[8];
#pragma unroll
    for (int t = 0; t < 8; ++t) {
      const int r = rt + t;
      const int a = (r >> 4) * SRS + (r & 15) * 16 + c;
      m[t] = sM[a];
      g[t] = sG[a];
    }

    short8 fP, fQ, fI, fB;
#pragma unroll
    for (int t = 0; t < 8; ++t) {
      const float mc = fminf(fmaxf(m[t], EPSF), 1.f - EPSF);
      const float lm = __log2f(mc);
      const float l1 = __log2f(1.f - mc);
      fP[t] = (short)bf16rne(LN2F * (l1 - lm));
      fQ[t] = (short)bf16rne(-LN2F * l1);
      fI[t] = (short)bf16rne(m[t]);
      fB[t] = (short)bf16rne(vv[ch][t] * g[t]);  // exact {0,1}
    }
    accP = __builtin_amdgcn_mfma_f32_16x16x32_bf16(fP, fB, accP, 0, 0, 0);
    accQ = __builtin_amdgcn_mfma_f32_16x16x32_bf16(fQ, fB, accQ, 0, 0, 0);
    accI = __builtin_amdgcn_mfma_f32_16x16x32_bf16(fI, fB, accI, 0, 0, 0);
  }

  // ---- block-level reduction: 4 waves -> 1, then one atomic flush ----
  __syncthreads();   // all LDS reads consumed (accumulators in registers)
#pragma unroll
  for (int r = 0; r < 4; ++r) {
    const int idx = (4 * q + r) * 16 + c;       // C/D: col=lane&15, row=q*4+r
    sBuf[wv * 768 + idx]        = accP[r];
    sBuf[3072 + wv * 768 + idx] = accQ[r];
    sBuf[6144 + wv * 768 + idx] = accI[r];
  }
  __syncthreads();

  const int rep = (int)blockIdx.x & (NREP - 1);
  float* wsb = ws + ((size_t)rep * NBATCH + b) * 768;
  {
    float sP = 0.f, sQ = 0.f, sI = 0.f;
#pragma unroll
    for (int wvv = 0; wvv < 4; ++wvv) {
      sP += sBuf[wvv * 768 + tid];
      sQ += sBuf[3072 + wvv * 768 + tid];
      sI += sBuf[6144 + wvv * 768 + tid];
    }
    unsafeAtomicAdd(&wsb[tid],       sP);
    unsafeAtomicAdd(&wsb[256 + tid], sQ);
    unsafeAtomicAdd(&wsb[512 + tid], sI);
  }
}

// ---------------- solve kernel ----------------
#define DPP_U(x, C) ((unsigned)__builtin_amdgcn_update_dpp(0, (int)(x), (C), 0xF, 0xF, true))

__device__ __forceinline__ float rowsum16(float x) {
  x += __uint_as_float(DPP_U(__float_as_uint(x), 0x128)); // row ror 8
  x += __uint_as_float(DPP_U(__float_as_uint(x), 0x124)); // row ror 4
  x += __uint_as_float(DPP_U(__float_as_uint(x), 0x122)); // row ror 2
  x += __uint_as_float(DPP_U(__float_as_uint(x), 0x121)); // row ror 1
  return x;
}
__device__ __forceinline__ unsigned rowmin16(unsigned x) {
  unsigned y;
  y = DPP_U(x, 0x128); x = (y < x) ? y : x;
  y = DPP_U(x, 0x124); x = (y < x) ? y : x;
  y = DPP_U(x, 0x122); x = (y < x) ? y : x;
  y = DPP_U(x, 0x121); x = (y < x) ? y : x;
  return x;
}
__device__ __forceinline__ float readlane_f(float x, int l) {
  return __int_as_float(__builtin_amdgcn_readlane(__float_as_int(x), l));
}
__device__ __forceinline__ int rfl(int x) { return __builtin_amdgcn_readfirstlane(x); }

__device__ __forceinline__ float sel16v(int idx,
  float x0, float x1, float x2, float x3, float x4, float x5, float x6, float x7,
  float x8, float x9, float x10, float x11, float x12, float x13, float x14, float x15)
{
  const float a0 = (idx & 1) ? x1  : x0;
  const float a1 = (idx & 1) ? x3  : x2;
  const float a2 = (idx & 1) ? x5  : x4;
  const float a3 = (idx & 1) ? x7  : x6;
  const float a4 = (idx & 1) ? x9  : x8;
  const float a5 = (idx & 1) ? x11 : x10;
  const float a6 = (idx & 1) ? x13 : x12;
  const float a7 = (idx & 1) ? x15 : x14;
  const float b0 = (idx & 2) ? a1 : a0;
  const float b1 = (idx & 2) ? a3 : a2;
  const float b2 = (idx & 2) ? a5 : a4;
  const float b3 = (idx & 2) ? a7 : a6;
  const float c0 = (idx & 4) ? b1 : b0;
  const float c1 = (idx & 4) ? b3 : b2;
  return (idx & 8) ? c1 : c0;
}

#define R16(M) M(0) M(1) M(2) M(3) M(4) M(5) M(6) M(7) M(8) M(9) M(10) M(11) M(12) M(13) M(14) M(15)
#define SEL16(p, idx) sel16v(idx, p##0,p##1,p##2,p##3,p##4,p##5,p##6,p##7,p##8,p##9,p##10,p##11,p##12,p##13,p##14,p##15)

#define LD3(i)  const float pc##i = sB[i*16 + col]; \
                const float qc##i = sB[256 + i*16 + col]; \
                const float ic##i = sB[512 + i*16 + col];
#define SGQS(i) sg += ic##i; qs += qc##i;
#define MKA(i)  const float Sm##i = rowsum16(ic##i); \
  const float a##i = WCE * (pc##i + rowsum16(qc##i)) / Vb \
                   + WDICE * (1.f - 2.f * ic##i / (Sm##i + sg + EPSF));
#define PKA(i)  const unsigned t##i = (__float_as_uint(a##i + 64.f) & 0xFFFFFFF0u) | (unsigned)i;

// R15 solve: R14 body + (a) removed the unnecessary post-load __syncthreads
// (each wave writes/reads only its own sAcc[w]; intra-wave LDS ordering is
// enforced by compiler lgkmcnt waits), (b) augmenting-row-reduction pass
// between column reduction and Dijkstra (unbundled from R12; invariants
// re-verified: a-u-v>=0 kept everywhere, exact tightness on assignment,
// ties prefer free column, bumped rows safely reprocessed; 24-step cap ->
// any partial state is a valid Dijkstra start).
__global__ __launch_bounds__(256, 1) void sml_solve(const float* __restrict__ ws,
                                                    float* __restrict__ out)
{
  const int tid = (int)threadIdx.x;
  const int w   = tid >> 6;
  const int l   = tid & 63;
  const int col = l & 15;
  __shared__ float sAcc[NBATCH][768];
  __shared__ float part[NBATCH][3];

  // ---- cooperative load + replica sum (wave-local; no barrier needed) ----
  float* sB = sAcc[w];
#pragma unroll
  for (int k = 0; k < 3; ++k) {
    const int idx4 = k * 64 + l;
    float4 s = {0.f, 0.f, 0.f, 0.f};
#pragma unroll
    for (int r = 0; r < NREP; ++r) {
      const float4 t = *(const float4*)(ws + ((size_t)r * NBATCH + w) * 768 + idx4 * 4);
      s.x += t.x; s.y += t.y; s.z += t.z; s.w += t.w;
    }
    *(float4*)&sB[idx4 * 4] = s;
  }

  R16(LD3)
  float sg = 0.f, qs = 0.f;
  R16(SGQS)
  const float V    = rowsum16(sg);
  const float Vb   = fmaxf(V, 1.f);
  const float Btot = rowsum16(qs);
  R16(MKA)

  // ---- column reduction: within-lane argmin over rows (register min-tree) --
  R16(PKA)
  unsigned mA, mB2, mC2, mD2;
  {
    const unsigned s0 = t0  < t1  ? t0  : t1;
    const unsigned s1 = t2  < t3  ? t2  : t3;
    const unsigned s2 = t4  < t5  ? t4  : t5;
    const unsigned s3 = t6  < t7  ? t6  : t7;
    const unsigned s4 = t8  < t9  ? t8  : t9;
    const unsigned s5 = t10 < t11 ? t10 : t11;
    const unsigned s6 = t12 < t13 ? t12 : t13;
    const unsigned s7 = t14 < t15 ? t14 : t15;
    mA  = s0 < s1 ? s0 : s1;
    mB2 = s2 < s3 ? s2 : s3;
    mC2 = s4 < s5 ? s4 : s5;
    mD2 = s6 < s7 ? s6 : s7;
  }
  const unsigned mAB  = mA  < mB2 ? mA  : mB2;
  const unsigned mCD  = mC2 < mD2 ? mC2 : mD2;
  const unsigned mall = mAB < mCD ? mAB : mCD;
  const int r0i = (int)(mall & 15u);      // argmin row of this lane's column
  float vdual = SEL16(a, r0i);            // EXACT column min -> tight duals

  unsigned long long pword = 0ull;        // nibble j = row assigned to col j
  unsigned pmask = 0u;                    // bit j = col j assigned
  unsigned rowused = 0u;                  // bit i = row i assigned
#pragma unroll
  for (int j = 0; j < 16; ++j) {
    const int rj = __builtin_amdgcn_readlane(r0i, j);
    if (!((rowused >> rj) & 1u)) {
      rowused |= 1u << rj;
      pmask   |= 1u << j;
      pword   |= (unsigned long long)rj << (4 * j);
    }
  }

  float u_t = 0.f;                        // u[row = l&15] (replicated per group)

  // ---- augmenting row reduction (classic JV), capped bump chains ----
  {
    int steps = 24;
    for (int i = 0; i < 16 && steps > 0; ++i) {
      if ((rowused >> i) & 1u) continue;
      int icur = i;
      while (steps-- > 0) {
        const float d = SEL16(a, icur) - vdual;   // fresh reduced row (u rebuilt)
        unsigned pk1 = (__float_as_uint(d + 64.f) & 0xFFFFFFF0u) | (unsigned)col;
        const unsigned m1 = rowmin16(pk1);
        const int j1 = rfl((int)(m1 & 15u));
        const unsigned pk2 = (col == j1) ? 0xFFFFFFFFu : pk1;
        const unsigned m2 = rowmin16(pk2);
        const int j2 = rfl((int)(m2 & 15u));
        const float d1 = readlane_f(d, j1);
        const float d2 = readlane_f(d, j2);
        const bool strict = d1 < d2;
        int jt = j1;
        if (strict) {
          if (col == j1) vdual -= (d2 - d1);      // v[j1] decreases (exact)
        } else {
          const bool occ1 = (pmask >> j1) & 1u;
          const bool occ2 = (pmask >> j2) & 1u;
          if (occ1 && !occ2) jt = j2;             // tie: prefer free column
        }
        if (col == icur) u_t = d2;                // u[icur] = second min
        const bool occ = (pmask >> jt) & 1u;
        const int owner = occ ? (int)((pword >> (4 * jt)) & 15ull) : -1;
        pword = (pword & ~(15ull << (4 * jt)))
              | ((unsigned long long)icur << (4 * jt));
        pmask   |= 1u << jt;
        rowused |= 1u << icur;
        if (owner >= 0) { rowused &= ~(1u << owner); icur = owner; }
        else break;                               // assigned a free column
      }
    }
  }

  // ---- Dijkstra phases for remaining free rows (verified R11 body) ----
  for (int i = 0; i < 16; ++i) {
    if ((rowused >> i) & 1u) continue;
    float minv = 1e30f;
    int   way  = -1;
    bool  used = false;
    float Dent = 0.f;
    float Dcum = 0.f;
    bool  intree = (col == i);
    int   i0 = i;
    int   j0 = -1;

    for (int it = 0; it < 17; ++it) {
      const float u0  = readlane_f(u_t, i0);
      const float cur = SEL16(a, i0) - u0 - vdual;
      if (!used && cur < minv) { minv = cur; way = j0; }
      unsigned pk = (__float_as_uint((used ? 1e30f : minv) + 64.f) & 0xFFFFFFF0u)
                  | (unsigned)col;
      pk = rowmin16(pk);
      const float delta = __uint_as_float(pk & 0xFFFFFFF0u) - 64.f;
      if (used) vdual -= delta; else minv -= delta;
      Dcum += delta;
      const int j1s = rfl((int)(pk & 15u));
      const int  pj1 = rfl((int)((pword >> (4 * j1s)) & 15ull));
      const bool asg = (pmask >> j1s) & 1u;
      j0 = j1s;
      if (!asg) break;                    // free column found
      used   = used   || (col == j1s);
      Dent   = (col == pj1) ? Dcum : Dent;
      intree = intree || (col == pj1);
      i0 = pj1;
    }
    u_t += intree ? (Dcum - Dent) : 0.f;  // phase-end row-dual update

    int jcur = rfl(j0);
    for (int s = 0; s < 17; ++s) {
      const int wy   = rfl(__builtin_amdgcn_readlane(way, jcur));
      const int prev = (wy >= 0) ? (int)((pword >> (4 * wy)) & 15ull) : i;
      pword = (pword & ~(15ull << (4 * jcur)))
            | ((unsigned long long)prev << (4 * jcur));
      pmask |= 1u << jcur;
      if (wy < 0) break;
      jcur = rfl(wy);
    }
  }

  // loss: lane col matched with row ri — all from registers.
  const int ri  = (int)((pword >> (4 * col)) & 15ull);
  const float pcm = SEL16(pc, ri);
  const float icm = SEL16(ic, ri);
  const float smv = SEL16(Sm, ri);
  const float cce = rowsum16(pcm);
  const float dce = rowsum16(1.f - 2.f * icm / (smv + sg + EPSF));
  if (l == 0) { part[w][0] = cce + Btot; part[w][1] = dce; part[w][2] = V; }
  __syncthreads();

  if (tid == 0) {
    float C = 0.f, D = 0.f, Vt = 0.f;
#pragma unroll
    for (int bb = 0; bb < NBATCH; ++bb) {
      C += part[bb][0]; D += part[bb][1]; Vt += part[bb][2];
    }
    Vt = fmaxf(Vt, 1.f);
    out[0] = WCE * C / (Vt * (float)KD) + WDICE * D / 64.f;
  }
}

extern "C" void kernel_launch(void* const* d_in, const int* in_sizes, int n_in,
                              void* d_out, int out_size, void* d_ws, size_t ws_size,
                              hipStream_t stream)
{
  (void)in_sizes; (void)n_in; (void)out_size; (void)ws_size;
  const float* mask  = (const float*)d_in[0];
  const float* gt    = (const float*)d_in[1];
  const float* valid = (const float*)d_in[2];
  float* out = (float*)d_out;
  float* ws  = (float*)d_ws;

  hipMemsetAsync(d_ws, 0, (size_t)NREP * NBATCH * 768 * sizeof(float), stream);

  dim3 grid((NROWS + 255) / 256, NBATCH);
  sml_accum<<<grid, 256, 0, stream>>>(mask, gt, valid, ws);
  sml_solve<<<1, 256, 0, stream>>>(ws, out);
}

// Round 16
// 102.376 us; speedup vs baseline: 1.0423x; 1.0423x over previous
//
#include <hip/hip_runtime.h>

#define NBATCH 4
#define NROWS  100000
#define KD     16
#define EPSF   1e-6f
#define WCE    2.0f
#define WDICE  0.1f
#define NREP   8
#define LN2F   0.6931471805599453f
#define SRS    272   // super-row stride: 1024B data + 64B pad -> 2-way banks (free)

typedef __attribute__((ext_vector_type(8))) short short8;
typedef __attribute__((ext_vector_type(4))) float f32x4;

__device__ __forceinline__ unsigned short bf16rne(float x) {
  unsigned u = __float_as_uint(x);
  unsigned r = u + 0x7FFFu + ((u >> 16) & 1u);
  return (unsigned short)(r >> 16);
}

__device__ __forceinline__ void async_copy16(const float* g, float* l) {
  __builtin_amdgcn_global_load_lds(
      (const __attribute__((address_space(1))) float*)g,
      (__attribute__((address_space(3))) float*)l, 16, 0, 0);
}

// ---------------- accumulation kernel (R14 best-known body) ----------------
// MFMA formulation: C[i][j] = sum_n A[n][i] * (v_n * gt[n][j]) via
// 16x16x32 bf16 MFMA; P/Q/I accumulated per block, block-reduced in LDS,
// flushed with one atomic set per block into 8 replicas. Padded staging
// (SRS=272) keeps global_load_lds lane-contiguity with 2-way (free) LDS banks.
// valid[] loads hoisted above the staging barrier to overlap the vmcnt drain.
__global__ __launch_bounds__(256, 4) void sml_accum(
    const float* __restrict__ mask, const float* __restrict__ gt,
    const float* __restrict__ valid, float* __restrict__ ws)
{
  const int b    = blockIdx.y;
  const int tid  = (int)threadIdx.x;
  const int lane = tid & 63;
  const int wv   = tid >> 6;
  const int q    = lane >> 4;      // quad: k-slice rows 8q..8q+7
  const int c    = lane & 15;      // feature / label column
  const int row0 = blockIdx.x * 256;

  __shared__ float sBuf[9216];
  float* sM = sBuf;                // staging: 16 super-rows x SRS
  float* sG = sBuf + 16 * SRS;     // staging: 16 super-rows x SRS

  const float* maskb  = mask  + (size_t)b * NROWS * KD;
  const float* gtb    = gt    + (size_t)b * NROWS * KD;
  const float* validb = valid + (size_t)b * NROWS;

#pragma unroll
  for (int i = 0; i < 4; ++i) {
    const int g   = i * 256 + tid;            // 16B chunk index (row*4 + colgrp)
    const int rg  = row0 + (g >> 2);
    const int rc  = (rg < NROWS) ? rg : (NROWS - 1);   // clamp tail
    const size_t off = (size_t)rc * KD + (size_t)(g & 3) * 4;
    const int dst = (g >> 6) * SRS + (g & 63) * 4;     // padded group placement
    async_copy16(maskb + off, &sM[dst]);
    async_copy16(gtb   + off, &sG[dst]);
  }

  // ---- hoisted valid loads (independent of LDS; overlap the stage drain) --
  float vv[2][8];
#pragma unroll
  for (int ch = 0; ch < 2; ++ch) {
    const int grow = row0 + wv * 64 + ch * 32 + 8 * q;
    if (grow + 7 < NROWS) {
      const float4 va  = *(const float4*)(validb + grow);
      const float4 vb4 = *(const float4*)(validb + grow + 4);
      vv[ch][0] = va.x;  vv[ch][1] = va.y;  vv[ch][2] = va.z;  vv[ch][3] = va.w;
      vv[ch][4] = vb4.x; vv[ch][5] = vb4.y; vv[ch][6] = vb4.z; vv[ch][7] = vb4.w;
    } else {
#pragma unroll
      for (int t = 0; t < 8; ++t)
        vv[ch][t] = (grow + t < NROWS) ? validb[grow + t] : 0.f;
    }
  }
  __syncthreads();

  f32x4 accP = {0.f, 0.f, 0.f, 0.f};
  f32x4 accQ = {0.f, 0.f, 0.f, 0.f};
  f32x4 accI = {0.f, 0.f, 0.f, 0.f};

#pragma unroll
  for (int ch = 0; ch < 2; ++ch) {
    const int rt = wv * 64 + ch * 32 + 8 * q;    // block-local row of this quad
    float m[8], g[8];
#pragma unroll
    for (int t = 0; t < 8; ++t) {
      const int r = rt + t;
      const int a = (r >> 4) * SRS + (r & 15) * 16 + c;
      m[t] = sM[a];
      g[t] = sG[a];
    }

    short8 fP, fQ, fI, fB;
#pragma unroll
    for (int t = 0; t < 8; ++t) {
      const float mc = fminf(fmaxf(m[t], EPSF), 1.f - EPSF);
      const float lm = __log2f(mc);
      const float l1 = __log2f(1.f - mc);
      fP[t] = (short)bf16rne(LN2F * (l1 - lm));
      fQ[t] = (short)bf16rne(-LN2F * l1);
      fI[t] = (short)bf16rne(m[t]);
      fB[t] = (short)bf16rne(vv[ch][t] * g[t]);  // exact {0,1}
    }
    accP = __builtin_amdgcn_mfma_f32_16x16x32_bf16(fP, fB, accP, 0, 0, 0);
    accQ = __builtin_amdgcn_mfma_f32_16x16x32_bf16(fQ, fB, accQ, 0, 0, 0);
    accI = __builtin_amdgcn_mfma_f32_16x16x32_bf16(fI, fB, accI, 0, 0, 0);
  }

  // ---- block-level reduction: 4 waves -> 1, then one atomic flush ----
  __syncthreads();   // all LDS reads consumed (accumulators in registers)
#pragma unroll
  for (int r = 0; r < 4; ++r) {
    const int idx = (4 * q + r) * 16 + c;       // C/D: col=lane&15, row=q*4+r
    sBuf[wv * 768 + idx]        = accP[r];
    sBuf[3072 + wv * 768 + idx] = accQ[r];
    sBuf[6144 + wv * 768 + idx] = accI[r];
  }
  __syncthreads();

  const int rep = (int)blockIdx.x & (NREP - 1);
  float* wsb = ws + ((size_t)rep * NBATCH + b) * 768;
  {
    float sP = 0.f, sQ = 0.f, sI = 0.f;
#pragma unroll
    for (int wvv = 0; wvv < 4; ++wvv) {
      sP += sBuf[wvv * 768 + tid];
      sQ += sBuf[3072 + wvv * 768 + tid];
      sI += sBuf[6144 + wvv * 768 + tid];
    }
    unsafeAtomicAdd(&wsb[tid],       sP);
    unsafeAtomicAdd(&wsb[256 + tid], sQ);
    unsafeAtomicAdd(&wsb[512 + tid], sI);
  }
}

// ---------------- solve kernel (R14 best-known body) -----------------------
#define DPP_U(x, C) ((unsigned)__builtin_amdgcn_update_dpp(0, (int)(x), (C), 0xF, 0xF, true))

__device__ __forceinline__ float rowsum16(float x) {
  x += __uint_as_float(DPP_U(__float_as_uint(x), 0x128)); // row ror 8
  x += __uint_as_float(DPP_U(__float_as_uint(x), 0x124)); // row ror 4
  x += __uint_as_float(DPP_U(__float_as_uint(x), 0x122)); // row ror 2
  x += __uint_as_float(DPP_U(__float_as_uint(x), 0x121)); // row ror 1
  return x;
}
__device__ __forceinline__ unsigned rowmin16(unsigned x) {
  unsigned y;
  y = DPP_U(x, 0x128); x = (y < x) ? y : x;
  y = DPP_U(x, 0x124); x = (y < x) ? y : x;
  y = DPP_U(x, 0x122); x = (y < x) ? y : x;
  y = DPP_U(x, 0x121); x = (y < x) ? y : x;
  return x;
}
__device__ __forceinline__ float readlane_f(float x, int l) {
  return __int_as_float(__builtin_amdgcn_readlane(__float_as_int(x), l));
}
__device__ __forceinline__ int rfl(int x) { return __builtin_amdgcn_readfirstlane(x); }

__device__ __forceinline__ float sel16v(int idx,
  float x0, float x1, float x2, float x3, float x4, float x5, float x6, float x7,
  float x8, float x9, float x10, float x11, float x12, float x13, float x14, float x15)
{
  const float a0 = (idx & 1) ? x1  : x0;
  const float a1 = (idx & 1) ? x3  : x2;
  const float a2 = (idx & 1) ? x5  : x4;
  const float a3 = (idx & 1) ? x7  : x6;
  const float a4 = (idx & 1) ? x9  : x8;
  const float a5 = (idx & 1) ? x11 : x10;
  const float a6 = (idx & 1) ? x13 : x12;
  const float a7 = (idx & 1) ? x15 : x14;
  const float b0 = (idx & 2) ? a1 : a0;
  const float b1 = (idx & 2) ? a3 : a2;
  const float b2 = (idx & 2) ? a5 : a4;
  const float b3 = (idx & 2) ? a7 : a6;
  const float c0 = (idx & 4) ? b1 : b0;
  const float c1 = (idx & 4) ? b3 : b2;
  return (idx & 8) ? c1 : c0;
}

#define R16(M) M(0) M(1) M(2) M(3) M(4) M(5) M(6) M(7) M(8) M(9) M(10) M(11) M(12) M(13) M(14) M(15)
#define SEL16(p, idx) sel16v(idx, p##0,p##1,p##2,p##3,p##4,p##5,p##6,p##7,p##8,p##9,p##10,p##11,p##12,p##13,p##14,p##15)

#define LD3(i)  const float pc##i = sB[i*16 + col]; \
                const float qc##i = sB[256 + i*16 + col]; \
                const float ic##i = sB[512 + i*16 + col];
#define SGQS(i) sg += ic##i; qs += qc##i;
#define MKA(i)  const float Sm##i = rowsum16(ic##i); \
  const float a##i = WCE * (pc##i + rowsum16(qc##i)) / Vb \
                   + WDICE * (1.f - 2.f * ic##i / (Sm##i + sg + EPSF));
#define PKA(i)  const unsigned t##i = (__float_as_uint(a##i + 64.f) & 0xFFFFFFF0u) | (unsigned)i;

__global__ __launch_bounds__(256, 1) void sml_solve(const float* __restrict__ ws,
                                                    float* __restrict__ out)
{
  const int tid = (int)threadIdx.x;
  const int w   = tid >> 6;
  const int l   = tid & 63;
  const int col = l & 15;
  __shared__ float sAcc[NBATCH][768];
  __shared__ float part[NBATCH][3];

  // ---- cooperative load + replica sum: pipelined float4 loads ----
  float* sB = sAcc[w];
#pragma unroll
  for (int k = 0; k < 3; ++k) {
    const int idx4 = k * 64 + l;
    float4 s = {0.f, 0.f, 0.f, 0.f};
#pragma unroll
    for (int r = 0; r < NREP; ++r) {
      const float4 t = *(const float4*)(ws + ((size_t)r * NBATCH + w) * 768 + idx4 * 4);
      s.x += t.x; s.y += t.y; s.z += t.z; s.w += t.w;
    }
    *(float4*)&sB[idx4 * 4] = s;
  }
  __syncthreads();

  R16(LD3)
  float sg = 0.f, qs = 0.f;
  R16(SGQS)
  const float V    = rowsum16(sg);
  const float Vb   = fmaxf(V, 1.f);
  const float Btot = rowsum16(qs);
  R16(MKA)

  // ---- column reduction: within-lane argmin over rows (register min-tree) --
  R16(PKA)
  unsigned mA, mB2, mC2, mD2;
  {
    const unsigned s0 = t0  < t1  ? t0  : t1;
    const unsigned s1 = t2  < t3  ? t2  : t3;
    const unsigned s2 = t4  < t5  ? t4  : t5;
    const unsigned s3 = t6  < t7  ? t6  : t7;
    const unsigned s4 = t8  < t9  ? t8  : t9;
    const unsigned s5 = t10 < t11 ? t10 : t11;
    const unsigned s6 = t12 < t13 ? t12 : t13;
    const unsigned s7 = t14 < t15 ? t14 : t15;
    mA  = s0 < s1 ? s0 : s1;
    mB2 = s2 < s3 ? s2 : s3;
    mC2 = s4 < s5 ? s4 : s5;
    mD2 = s6 < s7 ? s6 : s7;
  }
  const unsigned mAB  = mA  < mB2 ? mA  : mB2;
  const unsigned mCD  = mC2 < mD2 ? mC2 : mD2;
  const unsigned mall = mAB < mCD ? mAB : mCD;
  const int r0i = (int)(mall & 15u);      // argmin row of this lane's column
  float vdual = SEL16(a, r0i);            // EXACT column min -> tight duals

  unsigned long long pword = 0ull;        // nibble j = row assigned to col j
  unsigned pmask = 0u;                    // bit j = col j assigned
  unsigned rowused = 0u;                  // bit i = row i assigned
#pragma unroll
  for (int j = 0; j < 16; ++j) {
    const int rj = __builtin_amdgcn_readlane(r0i, j);
    if (!((rowused >> rj) & 1u)) {
      rowused |= 1u << rj;
      pmask   |= 1u << j;
      pword   |= (unsigned long long)rj << (4 * j);
    }
  }

  float u_t = 0.f;                        // u[row = l&15] (replicated per group)

  for (int i = 0; i < 16; ++i) {
    if ((rowused >> i) & 1u) continue;    // assigned by column reduction
    float minv = 1e30f;
    int   way  = -1;
    bool  used = false;
    float Dent = 0.f;
    float Dcum = 0.f;
    bool  intree = (col == i);
    int   i0 = i;
    int   j0 = -1;

    for (int it = 0; it < 17; ++it) {
      const float u0  = readlane_f(u_t, i0);
      const float cur = SEL16(a, i0) - u0 - vdual;
      if (!used && cur < minv) { minv = cur; way = j0; }
      unsigned pk = (__float_as_uint((used ? 1e30f : minv) + 64.f) & 0xFFFFFFF0u)
                  | (unsigned)col;
      pk = rowmin16(pk);
      const float delta = __uint_as_float(pk & 0xFFFFFFF0u) - 64.f;
      if (used) vdual -= delta; else minv -= delta;
      Dcum += delta;
      const int j1s = rfl((int)(pk & 15u));
      const int  pj1 = rfl((int)((pword >> (4 * j1s)) & 15ull));
      const bool asg = (pmask >> j1s) & 1u;
      j0 = j1s;
      if (!asg) break;                    // free column found
      used   = used   || (col == j1s);
      Dent   = (col == pj1) ? Dcum : Dent;
      intree = intree || (col == pj1);
      i0 = pj1;
    }
    u_t += intree ? (Dcum - Dent) : 0.f;  // phase-end row-dual update

    int jcur = rfl(j0);
    for (int s = 0; s < 17; ++s) {
      const int wy   = rfl(__builtin_amdgcn_readlane(way, jcur));
      const int prev = (wy >= 0) ? (int)((pword >> (4 * wy)) & 15ull) : i;
      pword = (pword & ~(15ull << (4 * jcur)))
            | ((unsigned long long)prev << (4 * jcur));
      pmask |= 1u << jcur;
      if (wy < 0) break;
      jcur = rfl(wy);
    }
  }

  // loss: lane col matched with row ri — all from registers.
  const int ri  = (int)((pword >> (4 * col)) & 15ull);
  const float pcm = SEL16(pc, ri);
  const float icm = SEL16(ic, ri);
  const float smv = SEL16(Sm, ri);
  const float cce = rowsum16(pcm);
  const float dce = rowsum16(1.f - 2.f * icm / (smv + sg + EPSF));
  if (l == 0) { part[w][0] = cce + Btot; part[w][1] = dce; part[w][2] = V; }
  __syncthreads();

  if (tid == 0) {
    float C = 0.f, D = 0.f, Vt = 0.f;
#pragma unroll
    for (int bb = 0; bb < NBATCH; ++bb) {
      C += part[bb][0]; D += part[bb][1]; Vt += part[bb][2];
    }
    Vt = fmaxf(Vt, 1.f);
    out[0] = WCE * C / (Vt * (float)KD) + WDICE * D / 64.f;
  }
}

extern "C" void kernel_launch(void* const* d_in, const int* in_sizes, int n_in,
                              void* d_out, int out_size, void* d_ws, size_t ws_size,
                              hipStream_t stream)
{
  (void)in_sizes; (void)n_in; (void)out_size; (void)ws_size;
  const float* mask  = (const float*)d_in[0];
  const float* gt    = (const float*)d_in[1];
  const float* valid = (const float*)d_in[2];
  float* out = (float*)d_out;
  float* ws  = (float*)d_ws;

  hipMemsetAsync(d_ws, 0, (size_t)NREP * NBATCH * 768 * sizeof(float), stream);

  dim3 grid((NROWS + 255) / 256, NBATCH);
  sml_accum<<<grid, 256, 0, stream>>>(mask, gt, valid, ws);
  sml_solve<<<1, 256, 0, stream>>>(ws, out);
}